// Round 1
// baseline (1028.474 us; speedup 1.0000x reference)
//
#include <hip/hip_runtime.h>
#include <math.h>

// AttentionEncoder: per node, attention over its K=32 neighbors (D=128).
// One wave (64 lanes) per node; lane owns 2 dims (float2). Neighbor slab
// (32 x float2 per lane = 64 VGPRs) is read from HBM exactly once and
// reused from registers for both the score dot-products and the weighted
// aggregation. Scores are wave-reduced via a full xor butterfly so every
// lane ends with all 32 scores -> softmax is lane-local.

constexpr int D = 128;
constexpr int K = 32;
constexpr int WAVES_PER_BLOCK = 4;

__global__ __launch_bounds__(256)
void AttentionEncoder_32650341384783_kernel(const float* __restrict__ h_n,
                                            const float* __restrict__ neighbor,
                                            float* __restrict__ out, int N) {
    const int wave = threadIdx.x >> 6;
    const int lane = threadIdx.x & 63;
    const int n = blockIdx.x * WAVES_PER_BLOCK + wave;
    if (n >= N) return;

    const int d0 = lane * 2;  // this lane's 2 dims
    const float2 h = *(const float2*)(h_n + (size_t)n * D + d0);
    const float* nb_base = neighbor + (size_t)n * K * D + d0;

    // Load all 32 neighbor fragments (512B coalesced per instruction,
    // 32 independent loads in flight per wave).
    float2 nb[K];
#pragma unroll
    for (int k = 0; k < K; ++k) {
        nb[k] = *(const float2*)(nb_base + (size_t)k * D);
    }

    // Per-lane partial dot products.
    float p[K];
#pragma unroll
    for (int k = 0; k < K; ++k) {
        p[k] = h.x * nb[k].x + h.y * nb[k].y;
    }

    // Full 64-lane xor butterfly: afterwards every lane holds the complete
    // dot product for every k.
#pragma unroll
    for (int off = 1; off < 64; off <<= 1) {
#pragma unroll
        for (int k = 0; k < K; ++k) {
            p[k] += __shfl_xor(p[k], off, 64);
        }
    }

    // Lane-local softmax over the 32 scores.
    const float scale = 0.08838834764831845f;  // 1/sqrt(128)
    float m = -INFINITY;
#pragma unroll
    for (int k = 0; k < K; ++k) {
        p[k] *= scale;
        m = fmaxf(m, p[k]);
    }
    float denom = 0.0f;
#pragma unroll
    for (int k = 0; k < K; ++k) {
        p[k] = __expf(p[k] - m);
        denom += p[k];
    }
    const float inv = 1.0f / denom;

    // Weighted aggregation — purely lane-local (neighbor frags in regs).
    float aggx = 0.0f, aggy = 0.0f;
#pragma unroll
    for (int k = 0; k < K; ++k) {
        const float w = p[k] * inv;
        aggx = fmaf(w, nb[k].x, aggx);
        aggy = fmaf(w, nb[k].y, aggy);
    }

    float2 o;
    o.x = h.x + aggx;
    o.y = h.y + aggy;
    *(float2*)(out + (size_t)n * D + d0) = o;
}

extern "C" void kernel_launch(void* const* d_in, const int* in_sizes, int n_in,
                              void* d_out, int out_size, void* d_ws, size_t ws_size,
                              hipStream_t stream) {
    const float* h_n = (const float*)d_in[0];
    const float* neighbor = (const float*)d_in[1];
    float* out = (float*)d_out;
    const int N = in_sizes[0] / D;  // B*N nodes (B=1)

    const int blocks = (N + WAVES_PER_BLOCK - 1) / WAVES_PER_BLOCK;
    AttentionEncoder_32650341384783_kernel<<<blocks, WAVES_PER_BLOCK * 64, 0, stream>>>(
        h_n, neighbor, out, N);
}